// Round 3
// baseline (71.484 us; speedup 1.0000x reference)
//
#include <hip/hip_runtime.h>
#include <hip/hip_bf16.h>
#include <hip/hip_cooperative_groups.h>

namespace cg = cooperative_groups;

// CRPS loss:
//   crps(p) = (1/N) sum_i |x_i - y| - (1/N^2) sum_{i<j} |x_i - x_j|
//   out = mean_p crps(p)
// N = 20 ensemble members (compile-time), P = B*C*D*H*W = 524288 points.
// Memory-bound: 44 MB irreducible traffic -> ~7 us floor at 6.3 TB/s.
// Single cooperative kernel: partials -> grid.sync -> block 0 final reduce
// (kills the second dispatch's launch + latency overhead).

constexpr int N_ENS = 20;

typedef float f4 __attribute__((ext_vector_type(4)));

__global__ __launch_bounds__(256) void crps_coop(
    const f4* __restrict__ fc,        // (N_ENS, nv) in float4 units
    const f4* __restrict__ obs,       // (nv)
    const float* __restrict__ fc_s,   // scalar views for tail
    const float* __restrict__ obs_s,
    float* __restrict__ partial,      // (gridDim.x) in d_ws
    float* __restrict__ out,
    int nv, int P)
{
    const int stride = gridDim.x * blockDim.x;
    const int gtid = blockIdx.x * blockDim.x + threadIdx.x;
    float local = 0.0f;

    for (int v = gtid; v < nv; v += stride) {
        f4 x[N_ENS];
        #pragma unroll
        for (int i = 0; i < N_ENS; ++i)
            x[i] = __builtin_nontemporal_load(&fc[(size_t)i * (size_t)nv + (size_t)v]);
        const f4 y = __builtin_nontemporal_load(&obs[v]);

        #pragma unroll
        for (int c = 0; c < 4; ++c) {
            float xc[N_ENS];
            #pragma unroll
            for (int i = 0; i < N_ENS; ++i) xc[i] = x[i][c];
            const float yc = y[c];

            float t1 = 0.0f;
            #pragma unroll
            for (int i = 0; i < N_ENS; ++i) t1 += fabsf(xc[i] - yc);

            float t2 = 0.0f;
            #pragma unroll
            for (int i = 0; i < N_ENS; ++i) {
                #pragma unroll
                for (int j = i + 1; j < N_ENS; ++j)
                    t2 += fabsf(xc[i] - xc[j]);
            }
            local += t1 * (1.0f / N_ENS) - t2 * (1.0f / (N_ENS * N_ENS));
        }
    }

    // scalar tail (P % 4 != 0) — no-op for P=524288
    for (int p = 4 * nv + gtid; p < P; p += stride) {
        float xc[N_ENS];
        #pragma unroll
        for (int i = 0; i < N_ENS; ++i) xc[i] = fc_s[(size_t)i * (size_t)P + p];
        const float yc = obs_s[p];
        float t1 = 0.0f, t2 = 0.0f;
        #pragma unroll
        for (int i = 0; i < N_ENS; ++i) t1 += fabsf(xc[i] - yc);
        #pragma unroll
        for (int i = 0; i < N_ENS; ++i) {
            #pragma unroll
            for (int j = i + 1; j < N_ENS; ++j)
                t2 += fabsf(xc[i] - xc[j]);
        }
        local += t1 * (1.0f / N_ENS) - t2 * (1.0f / (N_ENS * N_ENS));
    }

    // wave (64-lane) reduction
    #pragma unroll
    for (int off = 32; off > 0; off >>= 1)
        local += __shfl_down(local, off, 64);

    __shared__ float wsum[4];  // 256 threads = 4 waves
    const int lane = threadIdx.x & 63;
    const int wid  = threadIdx.x >> 6;
    if (lane == 0) wsum[wid] = local;
    __syncthreads();
    if (threadIdx.x == 0) {
        partial[blockIdx.x] = wsum[0] + wsum[1] + wsum[2] + wsum[3];
        __threadfence();  // make partial visible device-wide before grid sync
    }

    cg::this_grid().sync();

    if (blockIdx.x == 0) {
        double s = 0.0;
        for (int i = threadIdx.x; i < (int)gridDim.x; i += blockDim.x)
            s += (double)partial[i];

        #pragma unroll
        for (int off = 32; off > 0; off >>= 1)
            s += __shfl_down(s, off, 64);

        __shared__ double dsum[4];
        if (lane == 0) dsum[wid] = s;
        __syncthreads();
        if (threadIdx.x == 0) {
            double tot = dsum[0] + dsum[1] + dsum[2] + dsum[3];
            out[0] = (float)(tot / (double)P);
        }
    }
}

extern "C" void kernel_launch(void* const* d_in, const int* in_sizes, int n_in,
                              void* d_out, int out_size, void* d_ws, size_t ws_size,
                              hipStream_t stream) {
    const float* fc  = (const float*)d_in[0];
    const float* obs = (const float*)d_in[1];
    float* out = (float*)d_out;

    int P  = in_sizes[1];    // B*C*D*H*W = 524288
    int nv = P >> 2;         // float4 count per ensemble row = 131072

    const int block = 256;
    int nblocks = (nv + block - 1) / block;
    if (nblocks < 1) nblocks = 1;
    if (nblocks > 512) nblocks = 512;  // co-residency: 2 blocks/CU on 256 CUs

    float* partial = (float*)d_ws;     // nblocks floats

    const f4* fc4  = (const f4*)fc;
    const f4* obs4 = (const f4*)obs;

    void* args[] = { (void*)&fc4, (void*)&obs4, (void*)&fc, (void*)&obs,
                     (void*)&partial, (void*)&out, (void*)&nv, (void*)&P };

    hipLaunchCooperativeKernel((const void*)crps_coop,
                               dim3(nblocks), dim3(block),
                               args, 0, stream);
}

// Round 4
// 25.245 us; speedup vs baseline: 2.8317x; 2.8317x over previous
//
#include <hip/hip_runtime.h>
#include <hip/hip_bf16.h>

// CRPS loss:
//   crps(p) = (1/N) sum_i |x_i - y| - (1/N^2) sum_{i<j} |x_i - x_j|
//   out = mean_p crps(p)
// N = 20 ensemble members (compile-time), P = B*C*D*H*W = 524288 points.
// Memory-bound: 44 MB irreducible traffic -> ~7 us floor at 6.3 TB/s.
//
// Single dispatch: every block stores a partial, the LAST block to arrive
// (device-scope counter) reduces the partials and writes the scalar.
// Counter in d_ws is never reset: winner test uses (old % nblocks), and
// nblocks divides 2^32, so any initial garbage (0xAA poison) and any number
// of graph replays stay correct. Output is order-independent (fixed-index
// double sum), so the kernel is deterministic.

constexpr int N_ENS = 20;

typedef float f4 __attribute__((ext_vector_type(4)));

__global__ __launch_bounds__(256) void crps_fused(
    const f4* __restrict__ fc,        // (N_ENS, nv) in float4 units
    const f4* __restrict__ obs,       // (nv)
    const float* __restrict__ fc_s,   // scalar views for tail
    const float* __restrict__ obs_s,
    float* __restrict__ partial,      // (nblocks) in d_ws
    unsigned* __restrict__ counter,   // 1 uint in d_ws (never reset)
    float* __restrict__ out,
    int nv, int P, int nblocks)
{
    const int stride = gridDim.x * blockDim.x;
    const int gtid = blockIdx.x * blockDim.x + threadIdx.x;
    float local = 0.0f;

    for (int v = gtid; v < nv; v += stride) {
        f4 x[N_ENS];
        #pragma unroll
        for (int i = 0; i < N_ENS; ++i)
            x[i] = fc[(size_t)i * (size_t)nv + (size_t)v];
        const f4 y = obs[v];

        #pragma unroll
        for (int c = 0; c < 4; ++c) {
            float xc[N_ENS];
            #pragma unroll
            for (int i = 0; i < N_ENS; ++i) xc[i] = x[i][c];
            const float yc = y[c];

            float t1 = 0.0f;
            #pragma unroll
            for (int i = 0; i < N_ENS; ++i) t1 += fabsf(xc[i] - yc);

            float t2 = 0.0f;
            #pragma unroll
            for (int i = 0; i < N_ENS; ++i) {
                #pragma unroll
                for (int j = i + 1; j < N_ENS; ++j)
                    t2 += fabsf(xc[i] - xc[j]);
            }
            local += t1 * (1.0f / N_ENS) - t2 * (1.0f / (N_ENS * N_ENS));
        }
    }

    // scalar tail (P % 4 != 0) — no-op for P=524288
    for (int p = 4 * nv + gtid; p < P; p += stride) {
        float xc[N_ENS];
        #pragma unroll
        for (int i = 0; i < N_ENS; ++i) xc[i] = fc_s[(size_t)i * (size_t)P + p];
        const float yc = obs_s[p];
        float t1 = 0.0f, t2 = 0.0f;
        #pragma unroll
        for (int i = 0; i < N_ENS; ++i) t1 += fabsf(xc[i] - yc);
        #pragma unroll
        for (int i = 0; i < N_ENS; ++i) {
            #pragma unroll
            for (int j = i + 1; j < N_ENS; ++j)
                t2 += fabsf(xc[i] - xc[j]);
        }
        local += t1 * (1.0f / N_ENS) - t2 * (1.0f / (N_ENS * N_ENS));
    }

    // wave (64-lane) reduction
    #pragma unroll
    for (int off = 32; off > 0; off >>= 1)
        local += __shfl_down(local, off, 64);

    __shared__ float wsum[4];  // 256 threads = 4 waves
    __shared__ int winner;
    const int lane = threadIdx.x & 63;
    const int wid  = threadIdx.x >> 6;
    if (lane == 0) wsum[wid] = local;
    __syncthreads();
    if (threadIdx.x == 0) {
        float bsum = wsum[0] + wsum[1] + wsum[2] + wsum[3];
        __hip_atomic_store(&partial[blockIdx.x], bsum,
                           __ATOMIC_RELEASE, __HIP_MEMORY_SCOPE_AGENT);
        unsigned old = __hip_atomic_fetch_add(counter, 1u,
                           __ATOMIC_ACQ_REL, __HIP_MEMORY_SCOPE_AGENT);
        winner = ((old % (unsigned)nblocks) == (unsigned)(nblocks - 1));
    }
    __syncthreads();

    if (winner) {
        double s = 0.0;
        for (int i = threadIdx.x; i < nblocks; i += blockDim.x)
            s += (double)__hip_atomic_load(&partial[i],
                           __ATOMIC_ACQUIRE, __HIP_MEMORY_SCOPE_AGENT);

        #pragma unroll
        for (int off = 32; off > 0; off >>= 1)
            s += __shfl_down(s, off, 64);

        __shared__ double dsum[4];
        if (lane == 0) dsum[wid] = s;
        __syncthreads();
        if (threadIdx.x == 0) {
            double tot = dsum[0] + dsum[1] + dsum[2] + dsum[3];
            out[0] = (float)(tot / (double)P);
        }
    }
}

extern "C" void kernel_launch(void* const* d_in, const int* in_sizes, int n_in,
                              void* d_out, int out_size, void* d_ws, size_t ws_size,
                              hipStream_t stream) {
    const float* fc  = (const float*)d_in[0];
    const float* obs = (const float*)d_in[1];
    float* out = (float*)d_out;

    const int P  = in_sizes[1];   // B*C*D*H*W = 524288
    const int nv = P >> 2;        // float4 count per ensemble row = 131072

    const int block = 256;
    // nblocks: power of two (must divide 2^32 for the counter-mod trick),
    // capped at 512 (2 blocks/CU). Grid-stride covers any remainder.
    int want = (nv + block - 1) / block;
    if (want < 1) want = 1;
    int nblocks = 1;
    while (nblocks * 2 <= want && nblocks < 512) nblocks *= 2;

    // d_ws layout: [0..127] counter (uses first 4 bytes), [128..] partials
    unsigned* counter = (unsigned*)d_ws;
    float* partial = (float*)((char*)d_ws + 128);

    crps_fused<<<nblocks, block, 0, stream>>>(
        (const f4*)fc, (const f4*)obs, fc, obs,
        partial, counter, out, nv, P, nblocks);
}

// Round 5
// 24.198 us; speedup vs baseline: 2.9541x; 1.0432x over previous
//
#include <hip/hip_runtime.h>
#include <hip/hip_bf16.h>

// CRPS loss:
//   crps(p) = (1/N) sum_i |x_i - y| - (1/N^2) sum_{i<j} |x_i - x_j|
//   out = mean_p crps(p)
// N = 20 ensemble members (compile-time), P = B*C*D*H*W = 524288 points.
// Memory-bound: 44 MB irreducible traffic -> ~7 us floor at 6.3 TB/s
// (harness flushes L3 with a 268 MB fill between replays, so reads are cold).
//
// Structure: memset(out,0) node + ONE kernel; each block contributes its
// partial via one relaxed float atomicAdd (global_atomic_add_f32, no cache
// maintenance, device-scope by default). Ordering nondeterminism ~1e-5,
// threshold 1.19e-2.

constexpr int N_ENS = 20;

typedef float f4 __attribute__((ext_vector_type(4)));

__global__ __launch_bounds__(256) void crps_atomic(
    const f4* __restrict__ fc,        // (N_ENS, nv) in float4 units
    const f4* __restrict__ obs,       // (nv)
    const float* __restrict__ fc_s,   // scalar views for tail
    const float* __restrict__ obs_s,
    float* __restrict__ out,
    int nv, int P, float inv_total)
{
    const int stride = gridDim.x * blockDim.x;
    const int gtid = blockIdx.x * blockDim.x + threadIdx.x;
    float local = 0.0f;

    for (int v = gtid; v < nv; v += stride) {
        f4 x[N_ENS];
        #pragma unroll
        for (int i = 0; i < N_ENS; ++i)
            x[i] = fc[(size_t)i * (size_t)nv + (size_t)v];
        const f4 y = obs[v];

        #pragma unroll
        for (int c = 0; c < 4; ++c) {
            float xc[N_ENS];
            #pragma unroll
            for (int i = 0; i < N_ENS; ++i) xc[i] = x[i][c];
            const float yc = y[c];

            float t1 = 0.0f;
            #pragma unroll
            for (int i = 0; i < N_ENS; ++i) t1 += fabsf(xc[i] - yc);

            float t2 = 0.0f;
            #pragma unroll
            for (int i = 0; i < N_ENS; ++i) {
                #pragma unroll
                for (int j = i + 1; j < N_ENS; ++j)
                    t2 += fabsf(xc[i] - xc[j]);
            }
            local += t1 * (1.0f / N_ENS) - t2 * (1.0f / (N_ENS * N_ENS));
        }
    }

    // scalar tail (P % 4 != 0) — no-op for P=524288
    for (int p = 4 * nv + gtid; p < P; p += stride) {
        float xc[N_ENS];
        #pragma unroll
        for (int i = 0; i < N_ENS; ++i) xc[i] = fc_s[(size_t)i * (size_t)P + p];
        const float yc = obs_s[p];
        float t1 = 0.0f, t2 = 0.0f;
        #pragma unroll
        for (int i = 0; i < N_ENS; ++i) t1 += fabsf(xc[i] - yc);
        #pragma unroll
        for (int i = 0; i < N_ENS; ++i) {
            #pragma unroll
            for (int j = i + 1; j < N_ENS; ++j)
                t2 += fabsf(xc[i] - xc[j]);
        }
        local += t1 * (1.0f / N_ENS) - t2 * (1.0f / (N_ENS * N_ENS));
    }

    // wave (64-lane) reduction
    #pragma unroll
    for (int off = 32; off > 0; off >>= 1)
        local += __shfl_down(local, off, 64);

    __shared__ float wsum[4];  // 256 threads = 4 waves
    const int lane = threadIdx.x & 63;
    const int wid  = threadIdx.x >> 6;
    if (lane == 0) wsum[wid] = local;
    __syncthreads();
    if (threadIdx.x == 0) {
        float bsum = wsum[0] + wsum[1] + wsum[2] + wsum[3];
        atomicAdd(out, bsum * inv_total);   // relaxed, device-scope
    }
}

extern "C" void kernel_launch(void* const* d_in, const int* in_sizes, int n_in,
                              void* d_out, int out_size, void* d_ws, size_t ws_size,
                              hipStream_t stream) {
    const float* fc  = (const float*)d_in[0];
    const float* obs = (const float*)d_in[1];
    float* out = (float*)d_out;

    const int P  = in_sizes[1];   // B*C*D*H*W = 524288
    const int nv = P >> 2;        // float4 count per ensemble row = 131072

    const int block = 256;
    int nblocks = (nv + block - 1) / block;   // 512
    if (nblocks < 1) nblocks = 1;
    if (nblocks > 2048) nblocks = 2048;       // grid-stride covers rest

    hipMemsetAsync(out, 0, sizeof(float), stream);
    crps_atomic<<<nblocks, block, 0, stream>>>(
        (const f4*)fc, (const f4*)obs, fc, obs, out, nv, P, 1.0f / (float)P);
}

// Round 8
// 22.043 us; speedup vs baseline: 3.2430x; 1.0978x over previous
//
#include <hip/hip_runtime.h>
#include <hip/hip_bf16.h>

// CRPS loss:
//   crps(p) = (1/N) sum_i |x_i - y| - (1/N^2) sum_{i<j} |x_i - x_j|
//   out = mean_p crps(p)
// N = 20 ensemble members (compile-time), P = B*C*D*H*W = 524288 points.
// Memory-bound: 44 MB irreducible traffic -> ~7 us floor at 6.3 TB/s
// (harness flushes L3 with a 268 MB fill between replays -> cold reads).
//
// Structure: TWO kernels. Cross-block visibility via kernel boundary (the
// only cheap coherence fence on gfx950 — R4/R5/R6 showed in-kernel cross-XCD
// reduce either costs wbl2/invl2 cache maintenance (+6 us) or is incorrect).
// Main kernel: float2 per thread x 1024 blocks = 4 waves/SIMD (vs R2's 2)
// for better latency hiding over the 21 HBM streams; x[20] f2 = 40 VGPR.
// Reduce kernel: one wave, 16 loads/lane, double accumulation.

constexpr int N_ENS = 20;

typedef float f2 __attribute__((ext_vector_type(2)));

__global__ __launch_bounds__(256) void crps_partial_v2(
    const f2* __restrict__ fc,        // (N_ENS, nv2) in float2 units
    const f2* __restrict__ obs,       // (nv2)
    const float* __restrict__ fc_s,   // scalar views for tail
    const float* __restrict__ obs_s,
    float* __restrict__ partial,      // (gridDim.x)
    int nv2, int P)
{
    const int stride = gridDim.x * blockDim.x;
    const int gtid = blockIdx.x * blockDim.x + threadIdx.x;
    float local = 0.0f;

    for (int v = gtid; v < nv2; v += stride) {
        f2 x[N_ENS];
        #pragma unroll
        for (int i = 0; i < N_ENS; ++i)
            x[i] = fc[(size_t)i * (size_t)nv2 + (size_t)v];
        const f2 y = obs[v];

        #pragma unroll
        for (int c = 0; c < 2; ++c) {
            float xc[N_ENS];
            #pragma unroll
            for (int i = 0; i < N_ENS; ++i) xc[i] = x[i][c];
            const float yc = y[c];

            float t1 = 0.0f;
            #pragma unroll
            for (int i = 0; i < N_ENS; ++i) t1 += fabsf(xc[i] - yc);

            float t2 = 0.0f;
            #pragma unroll
            for (int i = 0; i < N_ENS; ++i) {
                #pragma unroll
                for (int j = i + 1; j < N_ENS; ++j)
                    t2 += fabsf(xc[i] - xc[j]);
            }
            local += t1 * (1.0f / N_ENS) - t2 * (1.0f / (N_ENS * N_ENS));
        }
    }

    // scalar tail (P % 2 != 0) — no-op for P=524288
    for (int p = 2 * nv2 + gtid; p < P; p += stride) {
        float xc[N_ENS];
        #pragma unroll
        for (int i = 0; i < N_ENS; ++i) xc[i] = fc_s[(size_t)i * (size_t)P + p];
        const float yc = obs_s[p];
        float t1 = 0.0f, t2 = 0.0f;
        #pragma unroll
        for (int i = 0; i < N_ENS; ++i) t1 += fabsf(xc[i] - yc);
        #pragma unroll
        for (int i = 0; i < N_ENS; ++i) {
            #pragma unroll
            for (int j = i + 1; j < N_ENS; ++j)
                t2 += fabsf(xc[i] - xc[j]);
        }
        local += t1 * (1.0f / N_ENS) - t2 * (1.0f / (N_ENS * N_ENS));
    }

    // wave (64-lane) reduction
    #pragma unroll
    for (int off = 32; off > 0; off >>= 1)
        local += __shfl_down(local, off, 64);

    __shared__ float wsum[4];  // 256 threads = 4 waves
    const int lane = threadIdx.x & 63;
    const int wid  = threadIdx.x >> 6;
    if (lane == 0) wsum[wid] = local;
    __syncthreads();
    if (threadIdx.x == 0)
        partial[blockIdx.x] = wsum[0] + wsum[1] + wsum[2] + wsum[3];
}

__global__ __launch_bounds__(64) void crps_reduce_w(
    const float* __restrict__ partial,
    int nblocks,
    float* __restrict__ out,
    float inv_total)
{
    double s = 0.0;
    for (int i = threadIdx.x; i < nblocks; i += 64)
        s += (double)partial[i];

    #pragma unroll
    for (int off = 32; off > 0; off >>= 1)
        s += __shfl_down(s, off, 64);

    if (threadIdx.x == 0)
        out[0] = (float)(s * (double)inv_total);
}

extern "C" void kernel_launch(void* const* d_in, const int* in_sizes, int n_in,
                              void* d_out, int out_size, void* d_ws, size_t ws_size,
                              hipStream_t stream) {
    const float* fc  = (const float*)d_in[0];
    const float* obs = (const float*)d_in[1];
    float* out = (float*)d_out;

    const int P   = in_sizes[1];   // B*C*D*H*W = 524288
    const int nv2 = P >> 1;        // float2 count per ensemble row = 262144

    const int block = 256;
    int nblocks = (nv2 + block - 1) / block;  // 1024
    if (nblocks < 1) nblocks = 1;
    if (nblocks > 2048) nblocks = 2048;       // grid-stride covers rest

    float* partial = (float*)d_ws;            // nblocks floats

    crps_partial_v2<<<nblocks, block, 0, stream>>>(
        (const f2*)fc, (const f2*)obs, fc, obs, partial, nv2, P);
    crps_reduce_w<<<1, 64, 0, stream>>>(partial, nblocks, out, 1.0f / (float)P);
}